// Round 15
// baseline (3833.187 us; speedup 1.0000x reference)
//
#include <hip/hip_runtime.h>
#include <hip/hip_bf16.h>
#include <math.h>

#define NN 40000
#define EE 640000
#define GG 16
#define LL 3
#define TE 16

#define STC 200           // cat row stride (ushorts), K=192
#define STH 136           // h1 row stride (ushorts), K=128
#define STE 72            // es / phh row stride (ushorts), K=64
#define PCAT (TE*STC)     // 3200
#define PH1  (TE*STH)     // 2176
#define PES  (TE*STE)     // 1152
#define SWP_ST 196        // Wphi fp32 row stride (16*196*4 = 12544B <= 12800B overlay)

typedef __attribute__((ext_vector_type(8))) short s8v;   // 8 bf16
typedef __attribute__((ext_vector_type(4))) float f4v;   // MFMA acc

__device__ __forceinline__ float silu_f(float x){ return x / (1.f + __expf(-x)); }
__device__ __forceinline__ float sigmoid_f(float x){ return 1.f / (1.f + __expf(-x)); }
__device__ __forceinline__ ushort f2b(float x){
  __hip_bfloat16 h = __float2bfloat16(x);
  return __builtin_bit_cast(ushort, h);
}
__device__ __forceinline__ float b2f(ushort u){
  uint x = ((uint)u) << 16;
  return __builtin_bit_cast(float, x);
}
// truncation-based hi/lo split
__device__ __forceinline__ void split2(float v, ushort &hi, ushort &lo){
  uint b = __builtin_bit_cast(uint, v);
  hi = (ushort)(b >> 16);
  float rem = v - __builtin_bit_cast(float, b & 0xffff0000u);
  lo = (ushort)(__builtin_bit_cast(uint, rem) >> 16);
}

// ---------------- edge geometry: UD[e] = {ux,uy,uz,dist} ----------------
__global__ void k_geom(const float* __restrict__ pos, const int* __restrict__ edges,
                       float4* __restrict__ UD){
  int e = blockIdx.x*blockDim.x + threadIdx.x;
  if(e >= EE) return;
  int s = edges[2*e], d = edges[2*e+1];
  float dx = pos[3*d]-pos[3*s], dy = pos[3*d+1]-pos[3*s+1], dz = pos[3*d+2]-pos[3*s+2];
  float r = sqrtf(dx*dx+dy*dy+dz*dz + 1e-12f);
  float ir = 1.f/r;
  UD[e] = make_float4(dx*ir, dy*ir, dz*ir, r);
}

// ---------------- per-graph node counts via binary search (gids sorted) ----------------
__global__ void k_counts(const int* __restrict__ gids, int* __restrict__ cnt){
  __shared__ int lb[GG+1];
  int g = threadIdx.x;
  if(g <= GG){
    int lo=0, hi=NN;
    while(lo<hi){ int m=(lo+hi)>>1; if(gids[m]<g) lo=m+1; else hi=m; }
    lb[g]=lo;
  }
  __syncthreads();
  if(g < GG) cnt[g] = lb[g+1]-lb[g];
}

// ---------------- dst histogram ----------------
__global__ void k_hist(const int* __restrict__ edges, int* __restrict__ HIST){
  int e = blockIdx.x*blockDim.x+threadIdx.x;
  if(e<EE) atomicAdd(&HIST[edges[2*e+1]], 1);
}

// ---------------- exclusive scan of HIST ----------------
__global__ void k_scan(const int* __restrict__ HIST, int* __restrict__ BASE){
  __shared__ int ps[256];
  int t = threadIdx.x;
  const int CH = (NN+255)/256;
  int lo = t*CH, hi = lo+CH; if(hi>NN) hi=NN; if(lo>NN) lo=NN;
  int s=0;
  for(int i=lo;i<hi;i++) s += HIST[i];
  ps[t]=s;
  __syncthreads();
  if(t==0){ int run=0; for(int i=0;i<256;i++){ int v=ps[i]; ps[i]=run; run+=v; } }
  __syncthreads();
  int run = ps[t];
  for(int i=lo;i<hi;i++){ BASE[i]=run; run += HIST[i]; }
}

// ---------------- scatter edges into dst-sorted order ----------------
__global__ void k_scatter(const int* __restrict__ edges, const int* __restrict__ BASE,
                          int* __restrict__ CUR,
                          int* __restrict__ SRCp, int* __restrict__ DSTp,
                          const float4* __restrict__ UD, float4* __restrict__ UDP){
  int e = blockIdx.x*blockDim.x+threadIdx.x;
  if(e>=EE) return;
  int d = edges[2*e+1];
  int s = edges[2*e];
  int pos = BASE[d] + atomicAdd(&CUR[d], 1);
  SRCp[pos] = s;
  DSTp[pos] = d;
  UDP[pos]  = UD[e];
}

// ---------------- weight prep: transposed hi/lo bf16 planes ----------------
__global__ void k_prep_w(const float* __restrict__ elW1, const float* __restrict__ elW2,
                         const float* __restrict__ inW,
                         const float* __restrict__ msgW2,
                         ushort* __restrict__ W1H, ushort* __restrict__ W1L,
                         ushort* __restrict__ W2H, ushort* __restrict__ W2L,
                         ushort* __restrict__ W3H, ushort* __restrict__ W3L,
                         ushort* __restrict__ M2H, ushort* __restrict__ M2L){
  int tid = blockIdx.x*256 + threadIdx.x;
  const int per = 24576 + 8192 + 12288 + 12288;   // 57344
  if(tid >= LL*per) return;
  int l = tid/per, r = tid - l*per;
  float w; ushort* dh; ushort* dl; int idx;
  if(r < 24576){                 // W1t[n][k] = el_W1[k][n], 128x192
    int n = r/192, k = r - n*192;
    w = elW1[l*24576 + k*128 + n];
    dh = W1H; dl = W1L; idx = l*24576 + r;
  } else if(r < 32768){          // W2t[n][k] = el_W2[k][n], 64x128
    int i = r - 24576; int n = i/128, k = i - n*128;
    w = elW2[l*8192 + k*64 + n];
    dh = W2H; dl = W2L; idx = l*8192 + i;
  } else if(r < 45056){          // W3t[n][k] = in_W[k][n], 192x64
    int i = r - 32768; int n = i/64, k = i - n*64;
    w = inW[l*12288 + k*192 + n];
    dh = W3H; dl = W3L; idx = l*12288 + i;
  } else {                       // M2t[n][k] = msg_W2[k][n], 192x64
    int i = r - 45056; int n = i/64, k = i - n*64;
    w = msgW2[l*12288 + k*192 + n];
    dh = M2H; dl = M2L; idx = l*12288 + i;
  }
  ushort hi = f2b(w);
  dh[idx] = hi;
  dl[idx] = f2b(w - b2f(hi));
}

// ---------------- initial projection (+ interleaved SHL plane) ----------------
__global__ void k_proj(const float* __restrict__ x,
                       const float* __restrict__ W1, const float* __restrict__ b1,
                       const float* __restrict__ W2, const float* __restrict__ b2,
                       float* __restrict__ S, ushort* __restrict__ SHL){
  int n = blockIdx.x*blockDim.x+threadIdx.x;
  if(n>=NN) return;
  float xr[32];
  #pragma unroll
  for(int k=0;k<32;k++) xr[k] = x[n*32+k];
  float h[32];
  #pragma unroll 4
  for(int j=0;j<32;j++){
    float a = b1[j];
    #pragma unroll
    for(int k=0;k<32;k++) a += xr[k]*W1[k*32+j];
    h[j] = silu_f(a);
  }
  #pragma unroll 4
  for(int d=0; d<64; d++){
    float a = b2[d];
    #pragma unroll
    for(int j=0;j<32;j++) a += h[j]*W2[j*64+d];
    S[n*64+d] = a;
    ushort hi = f2b(a);
    SHL[(size_t)n*128 + d] = hi;
    SHL[(size_t)n*128 + 64 + d] = f2b(a - b2f(hi));
  }
}

// ---------------- graph-LN partial sums ----------------
__global__ void k_ln_reduce(const float* __restrict__ S, const int* __restrict__ gids,
                            float* __restrict__ GS, float* __restrict__ GQ){
  __shared__ float ls[GG], lq[GG];
  int t = threadIdx.x;
  if(t<GG){ ls[t]=0.f; lq[t]=0.f; }
  __syncthreads();
  int n = blockIdx.x*blockDim.x+t;
  if(n<NN){
    const float4* p = reinterpret_cast<const float4*>(S + (size_t)n*64);
    float sm=0.f, sq=0.f;
    #pragma unroll
    for(int i=0;i<16;i++){ float4 v=p[i];
      sm += v.x+v.y+v.z+v.w;
      sq += v.x*v.x+v.y*v.y+v.z*v.z+v.w*v.w; }
    int g = gids[n];
    atomicAdd(&ls[g], sm); atomicAdd(&lq[g], sq);
  }
  __syncthreads();
  if(t<GG){ atomicAdd(&GS[t], ls[t]); atomicAdd(&GQ[t], lq[t]); }
}

__global__ void k_ln_final(const float* __restrict__ GS, const float* __restrict__ GQ,
                           const int* __restrict__ cnt,
                           float* __restrict__ MEANV, float* __restrict__ INVV){
  int g = threadIdx.x;
  if(g<GG){
    float c = (float)cnt[g]*64.f;
    float m = GS[g]/c, e2 = GQ[g]/c;
    MEANV[g]=m; INVV[g]=rsqrtf(e2 - m*m + 1e-5f);
  }
}

// ---------------- node pre: sn -> SN; phh = silu(sn@msgW1+b1) -> interleaved plane ----------------
__global__ void k_node_pre(const float* __restrict__ S, const int* __restrict__ gids,
                           const float* __restrict__ MEANV, const float* __restrict__ INVV,
                           const float* __restrict__ lng, const float* __restrict__ lnb,
                           const float* __restrict__ W1, const float* __restrict__ b1,
                           float* __restrict__ SN, ushort* __restrict__ PHH){
  int t = threadIdx.x, w = t>>6, lane = t&63;
  int n = blockIdx.x*4 + w;
  __shared__ float sh[4][65];
  if(n < NN){
    int g = gids[n];
    float snv = (S[(size_t)n*64+lane] - MEANV[g]) * INVV[g] * lng[lane] + lnb[lane];
    SN[(size_t)n*64+lane] = snv;
    sh[w][lane] = snv;
  }
  __syncthreads();
  if(n < NN){
    float a = b1[lane];
    #pragma unroll 8
    for(int k=0;k<64;k++) a += sh[w][k]*W1[k*64+lane];
    float v = silu_f(a);
    ushort h_, l_; split2(v, h_, l_);
    PHH[(size_t)n*128 + lane] = h_;
    PHH[(size_t)n*128 + 64 + lane] = l_;
  }
}

// ---------------- fused edge kernel: TE=16 tiles, 26.5KB LDS, high occupancy ----------------
__global__ __launch_bounds__(256,5) void k_edge(
    const ushort* __restrict__ SHL, const ushort* __restrict__ PHH,
    const ushort* __restrict__ V0b, const float4* __restrict__ UDP,
    const int* __restrict__ SRCp, const int* __restrict__ DSTp,
    const float* __restrict__ efW, const float* __restrict__ efb,
    const ushort* __restrict__ GW1H, const ushort* __restrict__ GW1L, const float* __restrict__ elb1,
    const ushort* __restrict__ GW2H, const ushort* __restrict__ GW2L, const float* __restrict__ elb2,
    const ushort* __restrict__ GW3H, const ushort* __restrict__ GW3L, const float* __restrict__ inb,
    const ushort* __restrict__ M2H, const ushort* __restrict__ M2L, const float* __restrict__ msgb2,
    const float* __restrict__ eiW, const float* __restrict__ eib,
    float* __restrict__ SN, float* __restrict__ V1, int hasV0)
{
  __shared__ __align__(16) ushort sCat[2*PCAT];   // cat hi/lo; later Wphi fp32 overlay
  __shared__ __align__(16) ushort sH1 [2*PH1];    // h1 hi/lo
  __shared__ __align__(16) ushort sEs [2*PES];    // phh hi/lo, then es hi/lo
  __shared__ int   sSrc[TE], sDst[TE];
  __shared__ float sUnit[TE*3];
  __shared__ float sGate[TE];

  const int t  = threadIdx.x;
  // XCD-aware bijective swizzle (gridDim.x = 40000, divisible by 8)
  const int cpx = gridDim.x >> 3;
  const int bid = (blockIdx.x & 7)*cpx + (blockIdx.x >> 3);
  const int p0 = bid * TE;
  const int w  = t >> 6, l = t & 63;
  const int lr = l & 15, lg = l >> 4;

  // ---- stage edge meta
  if(t < TE){
    int p = p0 + t;
    sSrc[t] = SRCp[p]; sDst[t] = DSTp[p];
    float4 ud = UDP[p];
    sUnit[3*t] = ud.x; sUnit[3*t+1] = ud.y; sUnit[3*t+2] = ud.z;
  }
  // ---- build cat hi/lo + gather phh hi/lo: 16 threads per edge
  {
    int e = t >> 4, sub = t & 15;
    int pg = p0 + e;
    if(sub < 8){
      int s = sub;
      int src = SRCp[pg];
      *reinterpret_cast<s8v*>(&sCat[e*STC + s*8]) =
          *reinterpret_cast<const s8v*>(&SHL[(size_t)src*128 + s*8]);
      *reinterpret_cast<s8v*>(&sCat[PCAT + e*STC + s*8]) =
          *reinterpret_cast<const s8v*>(&SHL[(size_t)src*128 + 64 + s*8]);
      float dist = UDP[pg].w;
      #pragma unroll
      for(int jj=0;jj<8;jj++){
        int j = s*8 + jj;
        float v = silu_f(dist*efW[j] + efb[j]);
        ushort h_, l_; split2(v, h_, l_);
        sCat[e*STC + 128 + j] = h_;
        sCat[PCAT + e*STC + 128 + j] = l_;
      }
    } else {
      int s = sub - 8;
      int src = SRCp[pg], dst = DSTp[pg];
      *reinterpret_cast<s8v*>(&sCat[e*STC + 64 + s*8]) =
          *reinterpret_cast<const s8v*>(&SHL[(size_t)dst*128 + s*8]);
      *reinterpret_cast<s8v*>(&sCat[PCAT + e*STC + 64 + s*8]) =
          *reinterpret_cast<const s8v*>(&SHL[(size_t)dst*128 + 64 + s*8]);
      *reinterpret_cast<s8v*>(&sEs[e*STE + s*8]) =
          *reinterpret_cast<const s8v*>(&PHH[(size_t)src*128 + s*8]);
      *reinterpret_cast<s8v*>(&sEs[PES + e*STE + s*8]) =
          *reinterpret_cast<const s8v*>(&PHH[(size_t)src*128 + 64 + s*8]);
    }
  }
  __syncthreads();

  // ---- phi-B: ph[jl] = phh @ M2 + b2 -> registers (C layout == GEMM3)
  f4v ph[3];
  {
    s8v ahp[2], alp[2];
    #pragma unroll
    for(int k=0;k<2;k++){
      int ro = lr*STE + k*32 + lg*8;
      ahp[k] = *reinterpret_cast<const s8v*>(&sEs[ro]);
      alp[k] = *reinterpret_cast<const s8v*>(&sEs[PES + ro]);
    }
    #pragma unroll
    for(int jl=0;jl<3;jl++){
      s8v bh[2], bl[2];
      #pragma unroll
      for(int k=0;k<2;k++){
        int o = (16*(3*w+jl)+lr)*64 + k*32 + lg*8;
        bh[k] = *reinterpret_cast<const s8v*>(&M2H[o]);
        bl[k] = *reinterpret_cast<const s8v*>(&M2L[o]);
      }
      float bv = msgb2[16*(3*w+jl) + lr];
      f4v acc = (f4v){bv,bv,bv,bv};
      #pragma unroll
      for(int k=0;k<2;k++){
        acc = __builtin_amdgcn_mfma_f32_16x16x32_bf16(ahp[k], bh[k], acc, 0,0,0);
        acc = __builtin_amdgcn_mfma_f32_16x16x32_bf16(alp[k], bh[k], acc, 0,0,0);
        acc = __builtin_amdgcn_mfma_f32_16x16x32_bf16(ahp[k], bl[k], acc, 0,0,0);
      }
      ph[jl] = acc;
    }
  }

  // ---- GEMM1: h1 = silu(cat @ W1 + b1); A-frags hoisted, W1 per jl
  {
    s8v ah[6], al[6];
    #pragma unroll
    for(int k=0;k<6;k++){
      int ro = lr*STC + k*32 + lg*8;
      ah[k] = *reinterpret_cast<const s8v*>(&sCat[ro]);
      al[k] = *reinterpret_cast<const s8v*>(&sCat[PCAT + ro]);
    }
    #pragma unroll
    for(int jl=0;jl<2;jl++){
      const int col = 16*(2*w+jl)+lr;
      float bv = elb1[col];
      f4v acc = (f4v){bv,bv,bv,bv};
      {
        s8v bh[6];
        #pragma unroll
        for(int k=0;k<6;k++) bh[k] = *reinterpret_cast<const s8v*>(&GW1H[col*192 + k*32 + lg*8]);
        #pragma unroll
        for(int k=0;k<6;k++){
          acc = __builtin_amdgcn_mfma_f32_16x16x32_bf16(ah[k], bh[k], acc, 0,0,0);
          acc = __builtin_amdgcn_mfma_f32_16x16x32_bf16(al[k], bh[k], acc, 0,0,0);
        }
      }
      {
        s8v bl[6];
        #pragma unroll
        for(int k=0;k<6;k++) bl[k] = *reinterpret_cast<const s8v*>(&GW1L[col*192 + k*32 + lg*8]);
        #pragma unroll
        for(int k=0;k<6;k++)
          acc = __builtin_amdgcn_mfma_f32_16x16x32_bf16(ah[k], bl[k], acc, 0,0,0);
      }
      #pragma unroll
      for(int r=0;r<4;r++){
        float v = silu_f(acc[r]);
        ushort h_, l_; split2(v, h_, l_);
        int o = (lg*4 + r)*STH + col;
        sH1[o] = h_;
        sH1[PH1 + o] = l_;
      }
    }
  }
  __syncthreads();

  // ---- GEMM2: es = h1 @ W2 + b2; writes over phh (dead)
  {
    s8v a2h[4], a2l[4];
    #pragma unroll
    for(int k=0;k<4;k++){
      int ro = lr*STH + k*32 + lg*8;
      a2h[k] = *reinterpret_cast<const s8v*>(&sH1[ro]);
      a2l[k] = *reinterpret_cast<const s8v*>(&sH1[PH1 + ro]);
    }
    const int col = 16*w + lr;
    float bv = elb2[col];
    f4v acc = (f4v){bv,bv,bv,bv};
    #pragma unroll
    for(int k=0;k<4;k++){
      int o = col*128 + k*32 + lg*8;
      s8v bh = *reinterpret_cast<const s8v*>(&GW2H[o]);
      s8v bl = *reinterpret_cast<const s8v*>(&GW2L[o]);
      acc = __builtin_amdgcn_mfma_f32_16x16x32_bf16(a2h[k], bh, acc, 0,0,0);
      acc = __builtin_amdgcn_mfma_f32_16x16x32_bf16(a2l[k], bh, acc, 0,0,0);
      acc = __builtin_amdgcn_mfma_f32_16x16x32_bf16(a2h[k], bl, acc, 0,0,0);
    }
    #pragma unroll
    for(int r=0;r<4;r++){
      ushort h_, l_; split2(acc[r], h_, l_);
      int o = (lg*4 + r)*STE + col;
      sEs[o] = h_;
      sEs[PES + o] = l_;
    }
  }
  __syncthreads();

  // ---- GEMM3: Wphi = (es @ inW + inb) * ph -> fp32 overlay (cat region, dead)
  float* sWp = reinterpret_cast<float*>(sCat);
  {
    s8v a3h[2], a3l[2];
    #pragma unroll
    for(int k=0;k<2;k++){
      int ro = lr*STE + k*32 + lg*8;
      a3h[k] = *reinterpret_cast<const s8v*>(&sEs[ro]);
      a3l[k] = *reinterpret_cast<const s8v*>(&sEs[PES + ro]);
    }
    #pragma unroll
    for(int jl=0;jl<3;jl++){
      const int n = 16*(3*w+jl) + lr;
      s8v bh[2], bl[2];
      #pragma unroll
      for(int k=0;k<2;k++){
        bh[k] = *reinterpret_cast<const s8v*>(&GW3H[n*64 + k*32 + lg*8]);
        bl[k] = *reinterpret_cast<const s8v*>(&GW3L[n*64 + k*32 + lg*8]);
      }
      float bv = inb[n];
      f4v acc = (f4v){bv,bv,bv,bv};
      #pragma unroll
      for(int k=0;k<2;k++){
        acc = __builtin_amdgcn_mfma_f32_16x16x32_bf16(a3h[k], bh[k], acc, 0,0,0);
        acc = __builtin_amdgcn_mfma_f32_16x16x32_bf16(a3l[k], bh[k], acc, 0,0,0);
        acc = __builtin_amdgcn_mfma_f32_16x16x32_bf16(a3h[k], bl[k], acc, 0,0,0);
      }
      #pragma unroll
      for(int r=0;r<4;r++)
        sWp[(lg*4 + r)*SWP_ST + n] = acc[r]*ph[jl][r];
    }
  }
  __syncthreads();

  // ---- gate per edge: wave w handles edges [4w, 4w+4)
  float ei = eiW[l];
  #pragma unroll
  for(int i=0;i<4;i++){
    int e = w*4 + i;
    float gp = sWp[e*SWP_ST + l] * ei;
    #pragma unroll
    for(int off=1; off<64; off<<=1) gp += __shfl_xor(gp, off);
    if(l==0) sGate[e] = sigmoid_f(gp + eib[0]);
  }
  __syncthreads();

  // ---- column-owner segmented accumulation (dst-sorted runs)
  if(w == 0){
    float acc = 0.f;
    #pragma unroll
    for(int p=0;p<TE;p++){
      acc += sWp[p*SWP_ST + l] * sGate[p];
      bool flush = (p==TE-1) || (sDst[p+1] != sDst[p]);
      if(flush){ atomicAdd(&SN[(size_t)sDst[p]*64 + l], acc); acc = 0.f; }
    }
  } else {
    int c = w-1;
    float acc = 0.f;
    #pragma unroll
    for(int p=0;p<TE;p++){
      float pvv = sWp[p*SWP_ST + 64 + l];
      float pvs = sWp[p*SWP_ST + 128 + l];
      float term = pvs*sUnit[p*3+c];
      if(hasV0){
        float v0 = b2f(V0b[(size_t)sSrc[p]*192 + c*64 + l]);
        term += v0*pvv;
      }
      acc += term * sGate[p];
      bool flush = (p==TE-1) || (sDst[p+1] != sDst[p]);
      if(flush){ atomicAdd(&V1[(size_t)sDst[p]*192 + c*64 + l], acc); acc = 0.f; }
    }
  }
}

// ---------------- node post: UV update (+ SHL/V0b mirrors) ----------------
__global__ void k_node_post(const float* __restrict__ SN, const float* __restrict__ V1,
                            const float* __restrict__ upUV,
                            const float* __restrict__ uvW1, const float* __restrict__ uvb1,
                            const float* __restrict__ uvW2, const float* __restrict__ uvb2,
                            float* __restrict__ Sout, float* __restrict__ V0,
                            ushort* __restrict__ SHL, ushort* __restrict__ V0b)
{
  int t = threadIdx.x, w = t>>6, j = t&63;
  int n = blockIdx.x*4 + w;
  __shared__ float vsh[4][3][64];
  __shared__ float cat2[4][129];
  __shared__ float hh[4][65];
  if(n < NN){
    #pragma unroll
    for(int c=0;c<3;c++) vsh[w][c][j] = V1[(size_t)n*192 + c*64 + j];
  }
  __syncthreads();
  float Uv[3]={0,0,0}, Vv[3]={0,0,0};
  float s_new = 0.f;
  if(n < NN){
    #pragma unroll 4
    for(int k=0;k<64;k++){
      float wu = upUV[k*128 + j];
      float wv = upUV[k*128 + 64 + j];
      #pragma unroll
      for(int c=0;c<3;c++){ float vk = vsh[w][c][k]; Uv[c] += vk*wu; Vv[c] += vk*wv; }
    }
    s_new = SN[(size_t)n*64 + j];
    float vn2 = Vv[0]*Vv[0]+Vv[1]*Vv[1]+Vv[2]*Vv[2];
    cat2[w][j] = sqrtf(vn2 + 1e-6f);
    cat2[w][64+j] = s_new;
  }
  __syncthreads();
  if(n<NN){
    float a = uvb1[j];
    #pragma unroll 8
    for(int k=0;k<128;k++) a += cat2[w][k]*uvW1[k*64+j];
    hh[w][j] = silu_f(a);
  }
  __syncthreads();
  if(n<NN){
    float a0=uvb2[j], a1=uvb2[64+j], a2=uvb2[128+j];
    #pragma unroll 4
    for(int k=0;k<64;k++){
      float h = hh[w][k];
      a0 += h*uvW2[k*192+j]; a1 += h*uvW2[k*192+64+j]; a2 += h*uvW2[k*192+128+j];
    }
    float inner = Uv[0]*Vv[0]+Uv[1]*Vv[1]+Uv[2]*Vv[2];
    float sval = s_new + a2 + a1*inner;
    Sout[(size_t)n*64+j] = sval;
    ushort hi = f2b(sval);
    SHL[(size_t)n*128 + j] = hi;
    SHL[(size_t)n*128 + 64 + j] = f2b(sval - b2f(hi));
    #pragma unroll
    for(int c=0;c<3;c++){
      float vv = vsh[w][c][j] + a0*Uv[c];
      V0[(size_t)n*192 + c*64 + j] = vv;
      V0b[(size_t)n*192 + c*64 + j] = f2b(vv);
    }
  }
}

extern "C" void kernel_launch(void* const* d_in, const int* in_sizes, int n_in,
                              void* d_out, int out_size, void* d_ws, size_t ws_size,
                              hipStream_t stream)
{
  const float* node_features  = (const float*)d_in[0];
  const float* node_positions = (const float*)d_in[1];
  const int*   edges          = (const int*)  d_in[2];
  const int*   gids           = (const int*)  d_in[3];
  const float* proj_W1 = (const float*)d_in[4];
  const float* proj_b1 = (const float*)d_in[5];
  const float* proj_W2 = (const float*)d_in[6];
  const float* proj_b2 = (const float*)d_in[7];
  const float* ef_W  = (const float*)d_in[8];
  const float* ef_b  = (const float*)d_in[9];
  const float* el_W1 = (const float*)d_in[10];
  const float* el_b1 = (const float*)d_in[11];
  const float* el_W2 = (const float*)d_in[12];
  const float* el_b2 = (const float*)d_in[13];
  const float* in_W  = (const float*)d_in[14];
  const float* in_b  = (const float*)d_in[15];
  const float* msg_W1= (const float*)d_in[16];
  const float* msg_b1= (const float*)d_in[17];
  const float* msg_W2= (const float*)d_in[18];
  const float* msg_b2= (const float*)d_in[19];
  const float* ei_W  = (const float*)d_in[20];
  const float* ei_b  = (const float*)d_in[21];
  const float* ln_g  = (const float*)d_in[22];
  const float* ln_b  = (const float*)d_in[23];
  const float* up_UV = (const float*)d_in[24];
  const float* uv_W1 = (const float*)d_in[25];
  const float* uv_b1 = (const float*)d_in[26];
  const float* uv_W2 = (const float*)d_in[27];
  const float* uv_b2 = (const float*)d_in[28];

  float* ws = (float*)d_ws;
  size_t off = 0;
  float*  S    = ws + off; off += (size_t)NN*64;
  float*  SN   = ws + off; off += (size_t)NN*64;
  float*  V0   = ws + off; off += (size_t)NN*192;
  float*  V1   = ws + off; off += (size_t)NN*192;
  float4* UD   = (float4*)(ws + off); off += (size_t)EE*4;
  float4* UDP  = (float4*)(ws + off); off += (size_t)EE*4;
  float*  GS   = ws + off; off += GG;
  float*  GQ   = ws + off; off += GG;
  float*  MEANV= ws + off; off += GG;
  float*  INVV = ws + off; off += GG;
  int*    CNT  = (int*)(ws + off); off += GG;
  off = (off + 3) & ~(size_t)3;          // 16B-align
  ushort* SHL  = (ushort*)(ws + off); off += (size_t)NN*64;   // [node][128] interleaved hi/lo
  ushort* PHH  = (ushort*)(ws + off); off += (size_t)NN*64;   // [node][128] interleaved hi/lo
  ushort* V0b  = (ushort*)(ws + off); off += (size_t)NN*96;
  ushort* W1H = (ushort*)(ws + off); off += (size_t)LL*24576/2;
  ushort* W1L = (ushort*)(ws + off); off += (size_t)LL*24576/2;
  ushort* W2H = (ushort*)(ws + off); off += (size_t)LL*8192/2;
  ushort* W2L = (ushort*)(ws + off); off += (size_t)LL*8192/2;
  ushort* W3H = (ushort*)(ws + off); off += (size_t)LL*12288/2;
  ushort* W3L = (ushort*)(ws + off); off += (size_t)LL*12288/2;
  ushort* M2H = (ushort*)(ws + off); off += (size_t)LL*12288/2;
  ushort* M2L = (ushort*)(ws + off); off += (size_t)LL*12288/2;
  int*    HIST = (int*)(ws + off); off += NN;
  int*    BASE = (int*)(ws + off); off += NN;
  int*    CUR  = (int*)(ws + off); off += NN;
  int*    SRCp = (int*)(ws + off); off += EE;
  int*    DSTp = (int*)(ws + off); off += EE;

  hipMemsetAsync(HIST, 0, NN*sizeof(int), stream);
  hipMemsetAsync(CUR,  0, NN*sizeof(int), stream);
  hipMemsetAsync(V0, 0, (size_t)NN*192*sizeof(float), stream);
  hipMemsetAsync(V0b, 0, (size_t)NN*192*sizeof(ushort), stream);

  k_geom   <<<(EE+255)/256, 256, 0, stream>>>(node_positions, edges, UD);
  k_counts <<<1, 32, 0, stream>>>(gids, CNT);
  k_proj   <<<(NN+255)/256, 256, 0, stream>>>(node_features, proj_W1, proj_b1, proj_W2, proj_b2, S, SHL);
  k_prep_w <<<(LL*57344+255)/256, 256, 0, stream>>>(el_W1, el_W2, in_W, msg_W2,
                   W1H, W1L, W2H, W2L, W3H, W3L, M2H, M2L);
  k_hist   <<<(EE+255)/256, 256, 0, stream>>>(edges, HIST);
  k_scan   <<<1, 256, 0, stream>>>(HIST, BASE);
  k_scatter<<<(EE+255)/256, 256, 0, stream>>>(edges, BASE, CUR, SRCp, DSTp, UD, UDP);

  for(int l=0; l<LL; l++){
    hipMemsetAsync(GS, 0, 2*GG*sizeof(float), stream);
    k_ln_reduce<<<(NN+255)/256, 256, 0, stream>>>(S, gids, GS, GQ);
    k_ln_final <<<1, 64, 0, stream>>>(GS, GQ, CNT, MEANV, INVV);
    k_node_pre <<<(NN+3)/4, 256, 0, stream>>>(S, gids, MEANV, INVV,
                   ln_g + l*64, ln_b + l*64,
                   msg_W1 + l*64*64, msg_b1 + l*64,
                   SN, PHH);
    hipMemcpyAsync(V1, V0, (size_t)NN*192*sizeof(float), hipMemcpyDeviceToDevice, stream);
    k_edge<<<EE/TE, 256, 0, stream>>>(SHL, PHH, V0b, UDP, SRCp, DSTp,
                   ef_W + l*64, ef_b + l*64,
                   W1H + l*24576, W1L + l*24576, el_b1 + l*128,
                   W2H + l*8192,  W2L + l*8192,  el_b2 + l*64,
                   W3H + l*12288, W3L + l*12288, in_b + l*192,
                   M2H + l*12288, M2L + l*12288, msg_b2 + l*192,
                   ei_W + l*64, ei_b + l, SN, V1, l > 0 ? 1 : 0);
    float* sout = (l == LL-1) ? (float*)d_out : S;
    k_node_post<<<(NN+3)/4, 256, 0, stream>>>(SN, V1,
                   up_UV + l*64*128,
                   uv_W1 + l*128*64, uv_b1 + l*64,
                   uv_W2 + l*64*192, uv_b2 + l*192, sout, V0, SHL, V0b);
  }
}

// Round 16
// 2418.972 us; speedup vs baseline: 1.5846x; 1.5846x over previous
//
#include <hip/hip_runtime.h>
#include <hip/hip_bf16.h>
#include <math.h>

#define NN 40000
#define EE 640000
#define GG 16
#define LL 3
#define TE 32

#define STC 200           // cat row stride (ushorts), K=192
#define STH 136           // h1 row stride (ushorts), K=128
#define STE 72            // es row stride (ushorts), K=64
#define PCAT (TE*STC)     // 6400
#define PH1  (TE*STH)     // 4352
#define PES  (TE*STE)     // 2304
#define SWP_ST 196        // Wphi fp32 row stride

typedef __attribute__((ext_vector_type(8))) short s8v;   // 8 bf16
typedef __attribute__((ext_vector_type(4))) float f4v;   // MFMA acc

__device__ __forceinline__ float silu_f(float x){ return x / (1.f + __expf(-x)); }
__device__ __forceinline__ float sigmoid_f(float x){ return 1.f / (1.f + __expf(-x)); }
__device__ __forceinline__ ushort f2b(float x){
  __hip_bfloat16 h = __float2bfloat16(x);
  return __builtin_bit_cast(ushort, h);
}
__device__ __forceinline__ float b2f(ushort u){
  uint x = ((uint)u) << 16;
  return __builtin_bit_cast(float, x);
}
// truncation-based hi/lo split
__device__ __forceinline__ void split2(float v, ushort &hi, ushort &lo){
  uint b = __builtin_bit_cast(uint, v);
  hi = (ushort)(b >> 16);
  float rem = v - __builtin_bit_cast(float, b & 0xffff0000u);
  lo = (ushort)(__builtin_bit_cast(uint, rem) >> 16);
}

// ---------------- edge geometry: UD[e] = {ux,uy,uz,dist} ----------------
__global__ void k_geom(const float* __restrict__ pos, const int* __restrict__ edges,
                       float4* __restrict__ UD){
  int e = blockIdx.x*blockDim.x + threadIdx.x;
  if(e >= EE) return;
  int s = edges[2*e], d = edges[2*e+1];
  float dx = pos[3*d]-pos[3*s], dy = pos[3*d+1]-pos[3*s+1], dz = pos[3*d+2]-pos[3*s+2];
  float r = sqrtf(dx*dx+dy*dy+dz*dz + 1e-12f);
  float ir = 1.f/r;
  UD[e] = make_float4(dx*ir, dy*ir, dz*ir, r);
}

// ---------------- per-graph node counts via binary search (gids sorted) ----------------
__global__ void k_counts(const int* __restrict__ gids, int* __restrict__ cnt){
  __shared__ int lb[GG+1];
  int g = threadIdx.x;
  if(g <= GG){
    int lo=0, hi=NN;
    while(lo<hi){ int m=(lo+hi)>>1; if(gids[m]<g) lo=m+1; else hi=m; }
    lb[g]=lo;
  }
  __syncthreads();
  if(g < GG) cnt[g] = lb[g+1]-lb[g];
}

// ---------------- dst histogram ----------------
__global__ void k_hist(const int* __restrict__ edges, int* __restrict__ HIST){
  int e = blockIdx.x*blockDim.x+threadIdx.x;
  if(e<EE) atomicAdd(&HIST[edges[2*e+1]], 1);
}

// ---------------- exclusive scan of HIST ----------------
__global__ void k_scan(const int* __restrict__ HIST, int* __restrict__ BASE){
  __shared__ int ps[256];
  int t = threadIdx.x;
  const int CH = (NN+255)/256;
  int lo = t*CH, hi = lo+CH; if(hi>NN) hi=NN; if(lo>NN) lo=NN;
  int s=0;
  for(int i=lo;i<hi;i++) s += HIST[i];
  ps[t]=s;
  __syncthreads();
  if(t==0){ int run=0; for(int i=0;i<256;i++){ int v=ps[i]; ps[i]=run; run+=v; } }
  __syncthreads();
  int run = ps[t];
  for(int i=lo;i<hi;i++){ BASE[i]=run; run += HIST[i]; }
}

// ---------------- scatter edges into dst-sorted order ----------------
__global__ void k_scatter(const int* __restrict__ edges, const int* __restrict__ BASE,
                          int* __restrict__ CUR,
                          int* __restrict__ SRCp, int* __restrict__ DSTp,
                          const float4* __restrict__ UD, float4* __restrict__ UDP){
  int e = blockIdx.x*blockDim.x+threadIdx.x;
  if(e>=EE) return;
  int d = edges[2*e+1];
  int s = edges[2*e];
  int pos = BASE[d] + atomicAdd(&CUR[d], 1);
  SRCp[pos] = s;
  DSTp[pos] = d;
  UDP[pos]  = UD[e];
}

// ---------------- weight prep: transposed hi/lo bf16 planes ----------------
__global__ void k_prep_w(const float* __restrict__ elW1, const float* __restrict__ elW2,
                         const float* __restrict__ inW,
                         ushort* __restrict__ W1H, ushort* __restrict__ W1L,
                         ushort* __restrict__ W2H, ushort* __restrict__ W2L,
                         ushort* __restrict__ W3H, ushort* __restrict__ W3L){
  int tid = blockIdx.x*256 + threadIdx.x;
  const int per = 24576 + 8192 + 12288;   // 45056
  if(tid >= LL*per) return;
  int l = tid/per, r = tid - l*per;
  float w; ushort* dh; ushort* dl; int idx;
  if(r < 24576){                 // W1t[n][k] = el_W1[k][n], 128x192
    int n = r/192, k = r - n*192;
    w = elW1[l*24576 + k*128 + n];
    dh = W1H; dl = W1L; idx = l*24576 + r;
  } else if(r < 32768){          // W2t[n][k] = el_W2[k][n], 64x128
    int i = r - 24576; int n = i/128, k = i - n*128;
    w = elW2[l*8192 + k*64 + n];
    dh = W2H; dl = W2L; idx = l*8192 + i;
  } else {                       // W3t[n][k] = in_W[k][n], 192x64
    int i = r - 32768; int n = i/64, k = i - n*64;
    w = inW[l*12288 + k*192 + n];
    dh = W3H; dl = W3L; idx = l*12288 + i;
  }
  ushort hi = f2b(w);
  dh[idx] = hi;
  dl[idx] = f2b(w - b2f(hi));
}

// ---------------- initial projection (+ interleaved SHL plane) ----------------
__global__ void k_proj(const float* __restrict__ x,
                       const float* __restrict__ W1, const float* __restrict__ b1,
                       const float* __restrict__ W2, const float* __restrict__ b2,
                       float* __restrict__ S, ushort* __restrict__ SHL){
  int n = blockIdx.x*blockDim.x+threadIdx.x;
  if(n>=NN) return;
  float xr[32];
  #pragma unroll
  for(int k=0;k<32;k++) xr[k] = x[n*32+k];
  float h[32];
  #pragma unroll 4
  for(int j=0;j<32;j++){
    float a = b1[j];
    #pragma unroll
    for(int k=0;k<32;k++) a += xr[k]*W1[k*32+j];
    h[j] = silu_f(a);
  }
  #pragma unroll 4
  for(int d=0; d<64; d++){
    float a = b2[d];
    #pragma unroll
    for(int j=0;j<32;j++) a += h[j]*W2[j*64+d];
    S[n*64+d] = a;
    ushort hi = f2b(a);
    SHL[(size_t)n*128 + d] = hi;
    SHL[(size_t)n*128 + 64 + d] = f2b(a - b2f(hi));
  }
}

// ---------------- graph-LN partial sums ----------------
__global__ void k_ln_reduce(const float* __restrict__ S, const int* __restrict__ gids,
                            float* __restrict__ GS, float* __restrict__ GQ){
  __shared__ float ls[GG], lq[GG];
  int t = threadIdx.x;
  if(t<GG){ ls[t]=0.f; lq[t]=0.f; }
  __syncthreads();
  int n = blockIdx.x*blockDim.x+t;
  if(n<NN){
    const float4* p = reinterpret_cast<const float4*>(S + (size_t)n*64);
    float sm=0.f, sq=0.f;
    #pragma unroll
    for(int i=0;i<16;i++){ float4 v=p[i];
      sm += v.x+v.y+v.z+v.w;
      sq += v.x*v.x+v.y*v.y+v.z*v.z+v.w*v.w; }
    int g = gids[n];
    atomicAdd(&ls[g], sm); atomicAdd(&lq[g], sq);
  }
  __syncthreads();
  if(t<GG){ atomicAdd(&GS[t], ls[t]); atomicAdd(&GQ[t], lq[t]); }
}

__global__ void k_ln_final(const float* __restrict__ GS, const float* __restrict__ GQ,
                           const int* __restrict__ cnt,
                           float* __restrict__ MEANV, float* __restrict__ INVV){
  int g = threadIdx.x;
  if(g<GG){
    float c = (float)cnt[g]*64.f;
    float m = GS[g]/c, e2 = GQ[g]/c;
    MEANV[g]=m; INVV[g]=rsqrtf(e2 - m*m + 1e-5f);
  }
}

// ---------------- node pre: sn -> SN; FULL phi = silu(sn@M1+b1)@M2+b2 -> hi/lo interleaved ----------------
__global__ void k_node_pre(const float* __restrict__ S, const int* __restrict__ gids,
                           const float* __restrict__ MEANV, const float* __restrict__ INVV,
                           const float* __restrict__ lng, const float* __restrict__ lnb,
                           const float* __restrict__ W1, const float* __restrict__ b1,
                           const float* __restrict__ W2, const float* __restrict__ b2,
                           float* __restrict__ SN, ushort* __restrict__ PHI2){
  int t = threadIdx.x, w = t>>6, lane = t&63;
  int n = blockIdx.x*4 + w;
  __shared__ float sh[4][65];
  __shared__ float hh[4][65];
  if(n < NN){
    int g = gids[n];
    float snv = (S[(size_t)n*64+lane] - MEANV[g]) * INVV[g] * lng[lane] + lnb[lane];
    SN[(size_t)n*64+lane] = snv;
    sh[w][lane] = snv;
  }
  __syncthreads();
  if(n < NN){
    float a = b1[lane];
    #pragma unroll 8
    for(int k=0;k<64;k++) a += sh[w][k]*W1[k*64+lane];
    hh[w][lane] = silu_f(a);
  }
  __syncthreads();
  if(n < NN){
    #pragma unroll
    for(int m=0;m<3;m++){
      int j = lane + 64*m;
      float a = b2[j];
      #pragma unroll 8
      for(int k=0;k<64;k++) a += hh[w][k]*W2[k*192+j];
      ushort h_, l_; split2(a, h_, l_);
      PHI2[(size_t)n*384 + 2*j]     = h_;
      PHI2[(size_t)n*384 + 2*j + 1] = l_;
    }
  }
}

// ---------------- fused edge kernel: r14 skeleton, phi fully hoisted, early prefetch ----------------
__global__ __launch_bounds__(256,3) void k_edge(
    const ushort* __restrict__ SHL, const ushort* __restrict__ PHI2,
    const ushort* __restrict__ V0b, const float4* __restrict__ UDP,
    const int* __restrict__ SRCp, const int* __restrict__ DSTp,
    const float* __restrict__ efW, const float* __restrict__ efb,
    const ushort* __restrict__ GW1H, const ushort* __restrict__ GW1L, const float* __restrict__ elb1,
    const ushort* __restrict__ GW2H, const ushort* __restrict__ GW2L, const float* __restrict__ elb2,
    const ushort* __restrict__ GW3H, const ushort* __restrict__ GW3L, const float* __restrict__ inb,
    const float* __restrict__ eiW, const float* __restrict__ eib,
    float* __restrict__ SN, float* __restrict__ V1, int hasV0)
{
  __shared__ __align__(16) ushort sCat[2*PCAT];   // cat hi/lo; later Wphi fp32 overlay
  __shared__ __align__(16) ushort sH1 [2*PH1];    // h1 hi/lo
  __shared__ __align__(16) ushort sEs [2*PES];    // es hi/lo
  __shared__ int   sSrc[TE], sDst[TE];
  __shared__ float sUnit[TE*3];
  __shared__ float sGate[TE];

  const int t  = threadIdx.x;
  // XCD-aware bijective swizzle (gridDim.x = 20000, divisible by 8)
  const int cpx = gridDim.x >> 3;
  const int bid = (blockIdx.x & 7)*cpx + (blockIdx.x >> 3);
  const int p0 = bid * TE;
  const int w  = t >> 6, l = t & 63;
  const int lr = l & 15, lg = l >> 4;

  // ---- stage edge meta
  if(t < TE){
    int p = p0 + t;
    sSrc[t] = SRCp[p]; sDst[t] = DSTp[p];
    float4 ud = UDP[p];
    sUnit[3*t] = ud.x; sUnit[3*t+1] = ud.y; sUnit[3*t+2] = ud.z;
  }
  // ---- build cat hi/lo: 8 threads per edge
  {
    int e = t >> 3, s = t & 7;
    int pg = p0 + e;
    int src = SRCp[pg], dst = DSTp[pg];
    float dist = UDP[pg].w;
    *reinterpret_cast<s8v*>(&sCat[e*STC + s*8]) =
        *reinterpret_cast<const s8v*>(&SHL[(size_t)src*128 + s*8]);
    *reinterpret_cast<s8v*>(&sCat[PCAT + e*STC + s*8]) =
        *reinterpret_cast<const s8v*>(&SHL[(size_t)src*128 + 64 + s*8]);
    *reinterpret_cast<s8v*>(&sCat[e*STC + 64 + s*8]) =
        *reinterpret_cast<const s8v*>(&SHL[(size_t)dst*128 + s*8]);
    *reinterpret_cast<s8v*>(&sCat[PCAT + e*STC + 64 + s*8]) =
        *reinterpret_cast<const s8v*>(&SHL[(size_t)dst*128 + 64 + s*8]);
    #pragma unroll
    for(int jj=0;jj<8;jj++){
      int j = s*8 + jj;
      float v = silu_f(dist*efW[j] + efb[j]);
      ushort h_, l_; split2(v, h_, l_);
      sCat[e*STC + 128 + j] = h_;
      sCat[PCAT + e*STC + 128 + j] = l_;
    }
  }
  __syncthreads();

  // ---- EARLY PREFETCH (hidden under GEMM chain):
  // phi values in GEMM3 C-layout: one 4B load per (rt,jl,r)
  uint phu[2][3][4];
  #pragma unroll
  for(int rt=0; rt<2; rt++){
    #pragma unroll
    for(int r=0;r<4;r++){
      int srcp = sSrc[16*rt + lg*4 + r];
      #pragma unroll
      for(int jl=0;jl<3;jl++){
        int n = 16*(3*w+jl) + lr;
        phu[rt][jl][r] = *reinterpret_cast<const uint*>(&PHI2[(size_t)srcp*384 + 2*n]);
      }
    }
  }
  // V0b epilogue rows (waves 1-3), consumed only at the very end
  ushort v0pre[TE];
  if(w > 0 && hasV0){
    int c = w-1;
    #pragma unroll
    for(int p=0;p<TE;p++)
      v0pre[p] = V0b[(size_t)sSrc[p]*192 + c*64 + l];
  }

  // ---- GEMM1: h1 = silu(cat @ W1 + b1); W1 hoisted per jl
  #pragma unroll
  for(int jl=0;jl<2;jl++){
    s8v bh[6], bl[6];
    #pragma unroll
    for(int k=0;k<6;k++){
      int o = (16*(2*w+jl)+lr)*192 + k*32 + lg*8;
      bh[k] = *reinterpret_cast<const s8v*>(&GW1H[o]);
      bl[k] = *reinterpret_cast<const s8v*>(&GW1L[o]);
    }
    #pragma unroll
    for(int rt=0; rt<2; rt++){
      s8v ah[6], al[6];
      #pragma unroll
      for(int k=0;k<6;k++){
        int ro = (16*rt+lr)*STC + k*32 + lg*8;
        ah[k] = *reinterpret_cast<const s8v*>(&sCat[ro]);
        al[k] = *reinterpret_cast<const s8v*>(&sCat[PCAT + ro]);
      }
      float bv = elb1[16*(2*w+jl)+lr];
      f4v acc = (f4v){bv,bv,bv,bv};
      #pragma unroll
      for(int k=0;k<6;k++){
        acc = __builtin_amdgcn_mfma_f32_16x16x32_bf16(ah[k], bh[k], acc, 0,0,0);
        acc = __builtin_amdgcn_mfma_f32_16x16x32_bf16(al[k], bh[k], acc, 0,0,0);
        acc = __builtin_amdgcn_mfma_f32_16x16x32_bf16(ah[k], bl[k], acc, 0,0,0);
      }
      #pragma unroll
      for(int r=0;r<4;r++){
        float v = silu_f(acc[r]);
        ushort h_, l_; split2(v, h_, l_);
        int o = (16*rt + lg*4 + r)*STH + 16*(2*w+jl) + lr;
        sH1[o] = h_;
        sH1[PH1 + o] = l_;
      }
    }
  }
  __syncthreads();

  // ---- GEMM2: es = h1 @ W2 + b2; W2 hoisted once
  {
    s8v bh[4], bl[4];
    #pragma unroll
    for(int k=0;k<4;k++){
      int o = (16*w+lr)*128 + k*32 + lg*8;
      bh[k] = *reinterpret_cast<const s8v*>(&GW2H[o]);
      bl[k] = *reinterpret_cast<const s8v*>(&GW2L[o]);
    }
    #pragma unroll
    for(int rt=0; rt<2; rt++){
      s8v a2h[4], a2l[4];
      #pragma unroll
      for(int k=0;k<4;k++){
        int ro = (16*rt+lr)*STH + k*32 + lg*8;
        a2h[k] = *reinterpret_cast<const s8v*>(&sH1[ro]);
        a2l[k] = *reinterpret_cast<const s8v*>(&sH1[PH1 + ro]);
      }
      float bv = elb2[16*w + lr];
      f4v acc = (f4v){bv,bv,bv,bv};
      #pragma unroll
      for(int k=0;k<4;k++){
        acc = __builtin_amdgcn_mfma_f32_16x16x32_bf16(a2h[k], bh[k], acc, 0,0,0);
        acc = __builtin_amdgcn_mfma_f32_16x16x32_bf16(a2l[k], bh[k], acc, 0,0,0);
        acc = __builtin_amdgcn_mfma_f32_16x16x32_bf16(a2h[k], bl[k], acc, 0,0,0);
      }
      #pragma unroll
      for(int r=0;r<4;r++){
        ushort h_, l_; split2(acc[r], h_, l_);
        int o = (16*rt + lg*4 + r)*STE + 16*w + lr;
        sEs[o] = h_;
        sEs[PES + o] = l_;
      }
    }
  }
  __syncthreads();

  // ---- GEMM3: Wphi = (es @ inW + inb) * phi -> fp32 overlay (cat region, dead)
  float* sWp = reinterpret_cast<float*>(sCat);
  #pragma unroll
  for(int jl=0;jl<3;jl++){
    const int n = 16*(3*w+jl) + lr;
    s8v bh[2], bl[2];
    #pragma unroll
    for(int k=0;k<2;k++){
      bh[k] = *reinterpret_cast<const s8v*>(&GW3H[n*64 + k*32 + lg*8]);
      bl[k] = *reinterpret_cast<const s8v*>(&GW3L[n*64 + k*32 + lg*8]);
    }
    #pragma unroll
    for(int rt=0; rt<2; rt++){
      s8v a3h[2], a3l[2];
      #pragma unroll
      for(int k=0;k<2;k++){
        int ro = (16*rt+lr)*STE + k*32 + lg*8;
        a3h[k] = *reinterpret_cast<const s8v*>(&sEs[ro]);
        a3l[k] = *reinterpret_cast<const s8v*>(&sEs[PES + ro]);
      }
      float bv = inb[n];
      f4v acc = (f4v){bv,bv,bv,bv};
      #pragma unroll
      for(int k=0;k<2;k++){
        acc = __builtin_amdgcn_mfma_f32_16x16x32_bf16(a3h[k], bh[k], acc, 0,0,0);
        acc = __builtin_amdgcn_mfma_f32_16x16x32_bf16(a3l[k], bh[k], acc, 0,0,0);
        acc = __builtin_amdgcn_mfma_f32_16x16x32_bf16(a3h[k], bl[k], acc, 0,0,0);
      }
      #pragma unroll
      for(int r=0;r<4;r++){
        uint u = phu[rt][jl][r];
        float phi = b2f((ushort)(u & 0xffffu)) + b2f((ushort)(u >> 16));
        sWp[(16*rt + lg*4 + r)*SWP_ST + n] = acc[r]*phi;
      }
    }
  }
  __syncthreads();

  // ---- gate per edge: wave w handles edges [8w, 8w+8)
  float ei = eiW[l];
  #pragma unroll
  for(int i=0;i<8;i++){
    int e = w*8 + i;
    float gp = sWp[e*SWP_ST + l] * ei;
    #pragma unroll
    for(int off=1; off<64; off<<=1) gp += __shfl_xor(gp, off);
    if(l==0) sGate[e] = sigmoid_f(gp + eib[0]);
  }
  __syncthreads();

  // ---- column-owner segmented accumulation (dst-sorted runs)
  if(w == 0){
    float acc = 0.f;
    #pragma unroll
    for(int p=0;p<TE;p++){
      acc += sWp[p*SWP_ST + l] * sGate[p];
      bool flush = (p==TE-1) || (sDst[p+1] != sDst[p]);
      if(flush){ atomicAdd(&SN[(size_t)sDst[p]*64 + l], acc); acc = 0.f; }
    }
  } else {
    int c = w-1;
    float acc = 0.f;
    #pragma unroll
    for(int p=0;p<TE;p++){
      float pvv = sWp[p*SWP_ST + 64 + l];
      float pvs = sWp[p*SWP_ST + 128 + l];
      float term = pvs*sUnit[p*3+c];
      if(hasV0) term += b2f(v0pre[p])*pvv;
      acc += term * sGate[p];
      bool flush = (p==TE-1) || (sDst[p+1] != sDst[p]);
      if(flush){ atomicAdd(&V1[(size_t)sDst[p]*192 + c*64 + l], acc); acc = 0.f; }
    }
  }
}

// ---------------- node post: UV update (+ SHL/V0b mirrors) ----------------
__global__ void k_node_post(const float* __restrict__ SN, const float* __restrict__ V1,
                            const float* __restrict__ upUV,
                            const float* __restrict__ uvW1, const float* __restrict__ uvb1,
                            const float* __restrict__ uvW2, const float* __restrict__ uvb2,
                            float* __restrict__ Sout, float* __restrict__ V0,
                            ushort* __restrict__ SHL, ushort* __restrict__ V0b)
{
  int t = threadIdx.x, w = t>>6, j = t&63;
  int n = blockIdx.x*4 + w;
  __shared__ float vsh[4][3][64];
  __shared__ float cat2[4][129];
  __shared__ float hh[4][65];
  if(n < NN){
    #pragma unroll
    for(int c=0;c<3;c++) vsh[w][c][j] = V1[(size_t)n*192 + c*64 + j];
  }
  __syncthreads();
  float Uv[3]={0,0,0}, Vv[3]={0,0,0};
  float s_new = 0.f;
  if(n < NN){
    #pragma unroll 4
    for(int k=0;k<64;k++){
      float wu = upUV[k*128 + j];
      float wv = upUV[k*128 + 64 + j];
      #pragma unroll
      for(int c=0;c<3;c++){ float vk = vsh[w][c][k]; Uv[c] += vk*wu; Vv[c] += vk*wv; }
    }
    s_new = SN[(size_t)n*64 + j];
    float vn2 = Vv[0]*Vv[0]+Vv[1]*Vv[1]+Vv[2]*Vv[2];
    cat2[w][j] = sqrtf(vn2 + 1e-6f);
    cat2[w][64+j] = s_new;
  }
  __syncthreads();
  if(n<NN){
    float a = uvb1[j];
    #pragma unroll 8
    for(int k=0;k<128;k++) a += cat2[w][k]*uvW1[k*64+j];
    hh[w][j] = silu_f(a);
  }
  __syncthreads();
  if(n<NN){
    float a0=uvb2[j], a1=uvb2[64+j], a2=uvb2[128+j];
    #pragma unroll 4
    for(int k=0;k<64;k++){
      float h = hh[w][k];
      a0 += h*uvW2[k*192+j]; a1 += h*uvW2[k*192+64+j]; a2 += h*uvW2[k*192+128+j];
    }
    float inner = Uv[0]*Vv[0]+Uv[1]*Vv[1]+Uv[2]*Vv[2];
    float sval = s_new + a2 + a1*inner;
    Sout[(size_t)n*64+j] = sval;
    ushort hi = f2b(sval);
    SHL[(size_t)n*128 + j] = hi;
    SHL[(size_t)n*128 + 64 + j] = f2b(sval - b2f(hi));
    #pragma unroll
    for(int c=0;c<3;c++){
      float vv = vsh[w][c][j] + a0*Uv[c];
      V0[(size_t)n*192 + c*64 + j] = vv;
      V0b[(size_t)n*192 + c*64 + j] = f2b(vv);
    }
  }
}

extern "C" void kernel_launch(void* const* d_in, const int* in_sizes, int n_in,
                              void* d_out, int out_size, void* d_ws, size_t ws_size,
                              hipStream_t stream)
{
  const float* node_features  = (const float*)d_in[0];
  const float* node_positions = (const float*)d_in[1];
  const int*   edges          = (const int*)  d_in[2];
  const int*   gids           = (const int*)  d_in[3];
  const float* proj_W1 = (const float*)d_in[4];
  const float* proj_b1 = (const float*)d_in[5];
  const float* proj_W2 = (const float*)d_in[6];
  const float* proj_b2 = (const float*)d_in[7];
  const float* ef_W  = (const float*)d_in[8];
  const float* ef_b  = (const float*)d_in[9];
  const float* el_W1 = (const float*)d_in[10];
  const float* el_b1 = (const float*)d_in[11];
  const float* el_W2 = (const float*)d_in[12];
  const float* el_b2 = (const float*)d_in[13];
  const float* in_W  = (const float*)d_in[14];
  const float* in_b  = (const float*)d_in[15];
  const float* msg_W1= (const float*)d_in[16];
  const float* msg_b1= (const float*)d_in[17];
  const float* msg_W2= (const float*)d_in[18];
  const float* msg_b2= (const float*)d_in[19];
  const float* ei_W  = (const float*)d_in[20];
  const float* ei_b  = (const float*)d_in[21];
  const float* ln_g  = (const float*)d_in[22];
  const float* ln_b  = (const float*)d_in[23];
  const float* up_UV = (const float*)d_in[24];
  const float* uv_W1 = (const float*)d_in[25];
  const float* uv_b1 = (const float*)d_in[26];
  const float* uv_W2 = (const float*)d_in[27];
  const float* uv_b2 = (const float*)d_in[28];

  float* ws = (float*)d_ws;
  size_t off = 0;
  float*  S    = ws + off; off += (size_t)NN*64;
  float*  SN   = ws + off; off += (size_t)NN*64;
  float*  V0   = ws + off; off += (size_t)NN*192;
  float*  V1   = ws + off; off += (size_t)NN*192;
  float4* UD   = (float4*)(ws + off); off += (size_t)EE*4;
  float4* UDP  = (float4*)(ws + off); off += (size_t)EE*4;
  float*  GS   = ws + off; off += GG;
  float*  GQ   = ws + off; off += GG;
  float*  MEANV= ws + off; off += GG;
  float*  INVV = ws + off; off += GG;
  int*    CNT  = (int*)(ws + off); off += GG;
  off = (off + 3) & ~(size_t)3;          // 16B-align
  ushort* SHL  = (ushort*)(ws + off); off += (size_t)NN*64;    // [node][128] hi|lo
  ushort* PHI2 = (ushort*)(ws + off); off += (size_t)NN*192;   // [node][384] col-interleaved hi/lo
  ushort* V0b  = (ushort*)(ws + off); off += (size_t)NN*96;
  ushort* W1H = (ushort*)(ws + off); off += (size_t)LL*24576/2;
  ushort* W1L = (ushort*)(ws + off); off += (size_t)LL*24576/2;
  ushort* W2H = (ushort*)(ws + off); off += (size_t)LL*8192/2;
  ushort* W2L = (ushort*)(ws + off); off += (size_t)LL*8192/2;
  ushort* W3H = (ushort*)(ws + off); off += (size_t)LL*12288/2;
  ushort* W3L = (ushort*)(ws + off); off += (size_t)LL*12288/2;
  int*    HIST = (int*)(ws + off); off += NN;
  int*    BASE = (int*)(ws + off); off += NN;
  int*    CUR  = (int*)(ws + off); off += NN;
  int*    SRCp = (int*)(ws + off); off += EE;
  int*    DSTp = (int*)(ws + off); off += EE;

  hipMemsetAsync(HIST, 0, NN*sizeof(int), stream);
  hipMemsetAsync(CUR,  0, NN*sizeof(int), stream);
  hipMemsetAsync(V0, 0, (size_t)NN*192*sizeof(float), stream);
  hipMemsetAsync(V0b, 0, (size_t)NN*192*sizeof(ushort), stream);

  k_geom   <<<(EE+255)/256, 256, 0, stream>>>(node_positions, edges, UD);
  k_counts <<<1, 32, 0, stream>>>(gids, CNT);
  k_proj   <<<(NN+255)/256, 256, 0, stream>>>(node_features, proj_W1, proj_b1, proj_W2, proj_b2, S, SHL);
  k_prep_w <<<(LL*45056+255)/256, 256, 0, stream>>>(el_W1, el_W2, in_W,
                   W1H, W1L, W2H, W2L, W3H, W3L);
  k_hist   <<<(EE+255)/256, 256, 0, stream>>>(edges, HIST);
  k_scan   <<<1, 256, 0, stream>>>(HIST, BASE);
  k_scatter<<<(EE+255)/256, 256, 0, stream>>>(edges, BASE, CUR, SRCp, DSTp, UD, UDP);

  for(int l=0; l<LL; l++){
    hipMemsetAsync(GS, 0, 2*GG*sizeof(float), stream);
    k_ln_reduce<<<(NN+255)/256, 256, 0, stream>>>(S, gids, GS, GQ);
    k_ln_final <<<1, 64, 0, stream>>>(GS, GQ, CNT, MEANV, INVV);
    k_node_pre <<<(NN+3)/4, 256, 0, stream>>>(S, gids, MEANV, INVV,
                   ln_g + l*64, ln_b + l*64,
                   msg_W1 + l*64*64, msg_b1 + l*64,
                   msg_W2 + l*64*192, msg_b2 + l*192,
                   SN, PHI2);
    hipMemcpyAsync(V1, V0, (size_t)NN*192*sizeof(float), hipMemcpyDeviceToDevice, stream);
    k_edge<<<EE/TE, 256, 0, stream>>>(SHL, PHI2, V0b, UDP, SRCp, DSTp,
                   ef_W + l*64, ef_b + l*64,
                   W1H + l*24576, W1L + l*24576, el_b1 + l*128,
                   W2H + l*8192,  W2L + l*8192,  el_b2 + l*64,
                   W3H + l*12288, W3L + l*12288, in_b + l*192,
                   ei_W + l*64, ei_b + l, SN, V1, l > 0 ? 1 : 0);
    float* sout = (l == LL-1) ? (float*)d_out : S;
    k_node_post<<<(NN+3)/4, 256, 0, stream>>>(SN, V1,
                   up_UV + l*64*128,
                   uv_W1 + l*128*64, uv_b1 + l*64,
                   uv_W2 + l*64*192, uv_b2 + l*192, sout, V0, SHL, V0b);
  }
}